// Round 2
// baseline (303.365 us; speedup 1.0000x reference)
//
#include <hip/hip_runtime.h>
#include <hip/hip_bf16.h>

// Problem constants
#define BATCH 16
#define CIN 8
#define COUT 8
#define HH 512
#define WW 512
#define KK 3
constexpr int TPX = 4;                       // pixels per thread along h
constexpr float EPS = 1e-5f;
constexpr float NPC = (float)BATCH * HH * WW; // per-channel element count

// native vector type for __builtin_nontemporal_store (HIP float4 is a class)
typedef float floatx4 __attribute__((ext_vector_type(4)));

// Workspace layout:
//   [0, 64)      : stats (16 floats: sum, sumsq per channel)
//   [260, 2316)  : 514-float zero region (zrow[-1..512] all zeros)
//   [4096, ...)  : bf16 conv output
// hipMemsetAsync zeroes the first 4096 bytes each launch.

// MODE 0: conv -> bf16 ws + stats atomics
// MODE 1: conv -> stats atomics only (no ws write)
// MODE 2: conv recompute -> normalize -> fp32 out (reads stats)
template <int MODE>
__global__ __launch_bounds__(256, 4)
void conv_kernel(const float* __restrict__ x,
                 const float* __restrict__ lin_w,
                 const float* __restrict__ gamma,
                 const float* __restrict__ beta,
                 __hip_bfloat16* __restrict__ ws_y,
                 float* __restrict__ stats,
                 float* __restrict__ out) {
    const int w  = blockIdx.x * 256 + threadIdx.x;   // 0..511
    const int h0 = blockIdx.y * TPX;                  // 0..508
    const int b  = blockIdx.z;

    // zero row: zrow[-1..512] are zeros (h-edge rows load from here; the
    // row-pointer select is block-uniform -> s_cselect, off the VALU pipe)
    const float* zrow = stats + 65;

    // hoisted per-row info (block-uniform)
    int rowoff[TPX + 2];
    bool rv[TPX + 2];
#pragma unroll
    for (int r = 0; r < TPX + 2; ++r) {
        const int hraw = h0 - 1 + r;
        const int hcl = min(max(hraw, 0), HH - 1);
        rowoff[r] = hcl * WW;
        rv[r] = (hraw >= 0) && (hraw < HH);
    }
    const int wm = max(w - 1, 0), wp = min(w + 1, WW - 1);
    const bool wl = (w >= 1), wr = (w <= WW - 2);
    const float* xb = x + (size_t)b * CIN * HH * WW;

    float acc[TPX][COUT];
#pragma unroll
    for (int px = 0; px < TPX; ++px)
#pragma unroll
        for (int oc = 0; oc < COUT; ++oc) acc[px][oc] = 0.f;

    // two named raw-load buffers (static indexing only -> stay in VGPRs)
    float rawA[TPX + 2][3], rawB[TPX + 2][3];

    auto issue = [&](float (&raw)[TPX + 2][3], int ic) {
        const float* xc = xb + (size_t)ic * (HH * WW);
#pragma unroll
        for (int r = 0; r < TPX + 2; ++r) {
            const float* xr = rv[r] ? (xc + rowoff[r]) : zrow; // scalar select
            raw[r][0] = xr[wm];
            raw[r][1] = xr[w];
            raw[r][2] = xr[wp];
        }
    };

    auto fmab = [&](float (&raw)[TPX + 2][3], int ic) {
        // w-edge masks: only 2 lanes per block need them; in-place, part of
        // the consume phase (does not gate the load issue of the other buffer)
#pragma unroll
        for (int r = 0; r < TPX + 2; ++r) {
            raw[r][0] = wl ? raw[r][0] : 0.f;
            raw[r][2] = wr ? raw[r][2] : 0.f;
        }
#pragma unroll
        for (int kh = 0; kh < KK; ++kh) {
#pragma unroll
            for (int kw = 0; kw < KK; ++kw) {
                const int p = kh * KK + kw;
#pragma unroll
                for (int px = 0; px < TPX; ++px) {
                    const float xval = raw[kh + px][kw];
#pragma unroll
                    for (int oc = 0; oc < COUT; ++oc) {
                        // uniform address -> s_load; SGPR operand in v_fmac
                        acc[px][oc] = fmaf(xval, lin_w[(ic * COUT + oc) * 9 + p],
                                           acc[px][oc]);
                    }
                }
            }
        }
    };

    // software pipeline: loads for channel ic+1 are in flight under the
    // FMA block of channel ic (counted vmcnt does the rest)
    issue(rawA, 0);
    for (int icp = 0; icp < CIN / 2; ++icp) {
        issue(rawB, 2 * icp + 1);
        fmab(rawA, 2 * icp);
        if (icp < CIN / 2 - 1) issue(rawA, 2 * icp + 2);
        fmab(rawB, 2 * icp + 1);
    }

    if (MODE == 0 || MODE == 1) {
        // per-thread channel sums
        float s[COUT], q[COUT];
#pragma unroll
        for (int oc = 0; oc < COUT; ++oc) {
            float ss = 0.f, qq = 0.f;
#pragma unroll
            for (int px = 0; px < TPX; ++px) {
                ss += acc[px][oc];
                qq = fmaf(acc[px][oc], acc[px][oc], qq);
            }
            s[oc] = ss; q[oc] = qq;
        }
        // wave (64-lane) reduce
#pragma unroll
        for (int off = 32; off > 0; off >>= 1) {
#pragma unroll
            for (int oc = 0; oc < COUT; ++oc) {
                s[oc] += __shfl_down(s[oc], off);
                q[oc] += __shfl_down(q[oc], off);
            }
        }
        __shared__ float reds[4][2 * COUT];
        const int lane = threadIdx.x & 63, wv = threadIdx.x >> 6;
        if (lane == 0) {
#pragma unroll
            for (int oc = 0; oc < COUT; ++oc) {
                reds[wv][oc] = s[oc];
                reds[wv][COUT + oc] = q[oc];
            }
        }
        __syncthreads();
        if (threadIdx.x < 2 * COUT) {
            float v = reds[0][threadIdx.x] + reds[1][threadIdx.x] +
                      reds[2][threadIdx.x] + reds[3][threadIdx.x];
            atomicAdd(&stats[threadIdx.x], v);
        }
        if (MODE == 0) {
#pragma unroll
            for (int oc = 0; oc < COUT; ++oc)
#pragma unroll
                for (int px = 0; px < TPX; ++px) {
                    size_t oidx = (((size_t)(b * COUT + oc)) * HH + (h0 + px)) * WW + w;
                    __hip_bfloat16 bv = __float2bfloat16(acc[px][oc]);
                    // ws is 64 MiB (> 32 MiB aggregate L2), streamed once:
                    // nontemporal store avoids write-allocate thrash
                    __builtin_nontemporal_store(
                        *(const unsigned short*)&bv,
                        (unsigned short*)(ws_y + oidx));
                }
        }
    } else { // MODE 2: normalize + relu + write
#pragma unroll
        for (int oc = 0; oc < COUT; ++oc) {
            const float mean = stats[oc] * (1.f / NPC);
            const float var  = stats[COUT + oc] * (1.f / NPC) - mean * mean;
            const float rstd = rsqrtf(var + EPS);
            const float sc = gamma[oc] * rstd;
            const float sh = fmaf(-mean, sc, beta[oc]);
#pragma unroll
            for (int px = 0; px < TPX; ++px) {
                size_t oidx = (((size_t)(b * COUT + oc)) * HH + (h0 + px)) * WW + w;
                __builtin_nontemporal_store(
                    fmaxf(fmaf(acc[px][oc], sc, sh), 0.f), out + oidx);
            }
        }
    }
}

// BN+ReLU from bf16 ws, 8 elements/thread
__global__ __launch_bounds__(256)
void bn_kernel(const __hip_bfloat16* __restrict__ ws_y,
               const float* __restrict__ stats,
               const float* __restrict__ gamma,
               const float* __restrict__ beta,
               float* __restrict__ out) {
    const size_t i8 = ((size_t)blockIdx.x * 256 + threadIdx.x) * 8;
    const int oc = (int)((i8 >> 18) & 7);  // HH*WW = 2^18
    const float mean = stats[oc] * (1.f / NPC);
    const float var  = stats[COUT + oc] * (1.f / NPC) - mean * mean;
    const float rstd = rsqrtf(var + EPS);
    const float sc = gamma[oc] * rstd;
    const float sh = fmaf(-mean, sc, beta[oc]);

    const uint4 u = *(const uint4*)((const char*)ws_y + i8 * 2);
    float v[8];
    v[0] = __uint_as_float(u.x << 16);
    v[1] = __uint_as_float(u.x & 0xffff0000u);
    v[2] = __uint_as_float(u.y << 16);
    v[3] = __uint_as_float(u.y & 0xffff0000u);
    v[4] = __uint_as_float(u.z << 16);
    v[5] = __uint_as_float(u.z & 0xffff0000u);
    v[6] = __uint_as_float(u.w << 16);
    v[7] = __uint_as_float(u.w & 0xffff0000u);
    floatx4 o0, o1;
    o0.x = fmaxf(fmaf(v[0], sc, sh), 0.f);
    o0.y = fmaxf(fmaf(v[1], sc, sh), 0.f);
    o0.z = fmaxf(fmaf(v[2], sc, sh), 0.f);
    o0.w = fmaxf(fmaf(v[3], sc, sh), 0.f);
    o1.x = fmaxf(fmaf(v[4], sc, sh), 0.f);
    o1.y = fmaxf(fmaf(v[5], sc, sh), 0.f);
    o1.z = fmaxf(fmaf(v[6], sc, sh), 0.f);
    o1.w = fmaxf(fmaf(v[7], sc, sh), 0.f);
    // out is never re-read: stream past L2 (native vector type for builtin)
    __builtin_nontemporal_store(o0, (floatx4*)(out + i8));
    __builtin_nontemporal_store(o1, (floatx4*)(out + i8 + 4));
}

extern "C" void kernel_launch(void* const* d_in, const int* in_sizes, int n_in,
                              void* d_out, int out_size, void* d_ws, size_t ws_size,
                              hipStream_t stream) {
    const float* x     = (const float*)d_in[0];
    const float* lin_w = (const float*)d_in[1];
    // d_in[2] = lin_b: a per-channel constant shift of conv output, which
    // BatchNorm subtracts back out exactly (mean shifts identically) -> unused.
    const float* gamma = (const float*)d_in[3];
    const float* beta  = (const float*)d_in[4];
    float* out = (float*)d_out;

    float* stats = (float*)d_ws;                                   // 16 floats + zero row
    __hip_bfloat16* ws_y = (__hip_bfloat16*)((char*)d_ws + 4096);  // conv output, bf16

    const size_t n_elem = (size_t)BATCH * COUT * HH * WW;          // 33,554,432
    const size_t need = 4096 + n_elem * 2;

    hipMemsetAsync(d_ws, 0, 4096, stream);  // zero stats + zero row (ws re-poisoned 0xAA)

    dim3 grid(WW / 256, HH / TPX, BATCH);
    if (ws_size >= need) {
        conv_kernel<0><<<grid, 256, 0, stream>>>(x, lin_w, gamma, beta, ws_y, stats, out);
        bn_kernel<<<(unsigned)(n_elem / (8 * 256)), 256, 0, stream>>>(ws_y, stats, gamma, beta, out);
    } else {
        conv_kernel<1><<<grid, 256, 0, stream>>>(x, lin_w, gamma, beta, ws_y, stats, out);
        conv_kernel<2><<<grid, 256, 0, stream>>>(x, lin_w, gamma, beta, ws_y, stats, out);
    }
}